// Round 1
// baseline (3779.497 us; speedup 1.0000x reference)
//
#include <hip/hip_runtime.h>

// Problem constants (from reference): B=8, T=4096 -> BT=32768 tokens
#define BT     32768
#define HIDDEN 512
#define DDIM   256
#define KCODE  1024
#define NQUANT 8

// ---------------------------------------------------------------------------
// cnorm: ||c||^2 for every code of every quantizer. grid = NQ*K blocks x 256.
// ---------------------------------------------------------------------------
__global__ __launch_bounds__(256) void cnorm_kernel(const float* __restrict__ cb,
                                                    float* __restrict__ cnorm) {
  __shared__ float red[256];
  const int code = blockIdx.x;
  const float v = cb[(size_t)code * DDIM + threadIdx.x];
  red[threadIdx.x] = v * v;
  __syncthreads();
  for (int s = 128; s > 0; s >>= 1) {
    if (threadIdx.x < s) red[threadIdx.x] += red[threadIdx.x + s];
    __syncthreads();
  }
  if (threadIdx.x == 0) cnorm[code] = red[0];
}

// ---------------------------------------------------------------------------
// NT GEMM: C[m][n] = sum_k A[m][k]*B[n][k] + bias[n]
// 64x64 tile / block, 256 threads (16x16), 4x4 per thread, transposed LDS
// tiles so the inner loop is 2x ds_read_b128 + 16 v_fma_f32.
// ---------------------------------------------------------------------------
__global__ __launch_bounds__(256) void gemm_nt(const float* __restrict__ A,
                                               const float* __restrict__ B,
                                               const float* __restrict__ bias,
                                               float* __restrict__ C,
                                               int N, int K) {
  __shared__ float AsT[64][68];
  __shared__ float BsT[64][68];
  const int tid = threadIdx.x;
  const int tx = tid & 15, ty = tid >> 4;
  const int m0 = blockIdx.x * 64, n0 = blockIdx.y * 64;
  float acc[4][4] = {{0.f}};
  for (int kc = 0; kc < K; kc += 64) {
    __syncthreads();
#pragma unroll
    for (int v = 0; v < 4; ++v) {
      const int flat = v * 256 + tid;
      const int row = flat >> 4, seg = flat & 15;
      const float4 a4 = *(const float4*)&A[(size_t)(m0 + row) * K + kc + seg * 4];
      AsT[seg * 4 + 0][row] = a4.x; AsT[seg * 4 + 1][row] = a4.y;
      AsT[seg * 4 + 2][row] = a4.z; AsT[seg * 4 + 3][row] = a4.w;
      const float4 b4 = *(const float4*)&B[(size_t)(n0 + row) * K + kc + seg * 4];
      BsT[seg * 4 + 0][row] = b4.x; BsT[seg * 4 + 1][row] = b4.y;
      BsT[seg * 4 + 2][row] = b4.z; BsT[seg * 4 + 3][row] = b4.w;
    }
    __syncthreads();
#pragma unroll
    for (int k = 0; k < 64; ++k) {
      const float4 a = *(const float4*)&AsT[k][ty * 4];
      const float4 b = *(const float4*)&BsT[k][tx * 4];
      acc[0][0] += a.x * b.x; acc[0][1] += a.x * b.y; acc[0][2] += a.x * b.z; acc[0][3] += a.x * b.w;
      acc[1][0] += a.y * b.x; acc[1][1] += a.y * b.y; acc[1][2] += a.y * b.z; acc[1][3] += a.y * b.w;
      acc[2][0] += a.z * b.x; acc[2][1] += a.z * b.y; acc[2][2] += a.z * b.z; acc[2][3] += a.z * b.w;
      acc[3][0] += a.w * b.x; acc[3][1] += a.w * b.y; acc[3][2] += a.w * b.z; acc[3][3] += a.w * b.w;
    }
  }
  const float4 bb = *(const float4*)&bias[n0 + tx * 4];
#pragma unroll
  for (int i = 0; i < 4; ++i) {
    float4 o;
    o.x = acc[i][0] + bb.x; o.y = acc[i][1] + bb.y;
    o.z = acc[i][2] + bb.z; o.w = acc[i][3] + bb.w;
    *(float4*)&C[(size_t)(m0 + ty * 4 + i) * N + n0 + tx * 4] = o;
  }
}

// ---------------------------------------------------------------------------
// One RVQ step: distance GEMM (64 tokens x 1024 codes, D=256) with fused
// per-row argmin (first-occurrence tie-break), then gather/commit/residual
// update. grid = BT/64 blocks x 256 threads.
// d' = cnorm[c] - 2*(r.c)  (dropping ||r||^2: constant per row, argmin-safe)
// ---------------------------------------------------------------------------
__global__ __launch_bounds__(256) void rvq_step(float* __restrict__ r,
                                                const float* __restrict__ cb,
                                                const float* __restrict__ cnorm,
                                                float* __restrict__ qsum,
                                                float* __restrict__ q1,
                                                float* __restrict__ q2,
                                                float* __restrict__ commitAcc,
                                                int nq) {
  __shared__ float rsT[64][68];
  __shared__ float csT[64][68];
  __shared__ float redv[64][16];
  __shared__ int   redi[64][16];
  __shared__ float bestv[64];
  __shared__ int   besti[64];
  __shared__ float redc[256];
  const int tid = threadIdx.x;
  const int tx = tid & 15, ty = tid >> 4;
  const int m0 = blockIdx.x * 64;
  if (tid < 64) { bestv[tid] = 3.0e38f; besti[tid] = 0; }

  for (int nc = 0; nc < KCODE / 64; ++nc) {
    float acc[4][4] = {{0.f}};
    for (int kc = 0; kc < DDIM; kc += 64) {
      __syncthreads();
#pragma unroll
      for (int v = 0; v < 4; ++v) {
        const int flat = v * 256 + tid;
        const int row = flat >> 4, seg = flat & 15;
        const float4 a4 = *(const float4*)&r[(size_t)(m0 + row) * DDIM + kc + seg * 4];
        rsT[seg * 4 + 0][row] = a4.x; rsT[seg * 4 + 1][row] = a4.y;
        rsT[seg * 4 + 2][row] = a4.z; rsT[seg * 4 + 3][row] = a4.w;
        const float4 b4 = *(const float4*)&cb[(size_t)(nc * 64 + row) * DDIM + kc + seg * 4];
        csT[seg * 4 + 0][row] = b4.x; csT[seg * 4 + 1][row] = b4.y;
        csT[seg * 4 + 2][row] = b4.z; csT[seg * 4 + 3][row] = b4.w;
      }
      __syncthreads();
#pragma unroll
      for (int k = 0; k < 64; ++k) {
        const float4 a = *(const float4*)&rsT[k][ty * 4];
        const float4 b = *(const float4*)&csT[k][tx * 4];
        acc[0][0] += a.x * b.x; acc[0][1] += a.x * b.y; acc[0][2] += a.x * b.z; acc[0][3] += a.x * b.w;
        acc[1][0] += a.y * b.x; acc[1][1] += a.y * b.y; acc[1][2] += a.y * b.z; acc[1][3] += a.y * b.w;
        acc[2][0] += a.z * b.x; acc[2][1] += a.z * b.y; acc[2][2] += a.z * b.z; acc[2][3] += a.z * b.w;
        acc[3][0] += a.w * b.x; acc[3][1] += a.w * b.y; acc[3][2] += a.w * b.z; acc[3][3] += a.w * b.w;
      }
    }
    // distances + per-thread argmin over this thread's 4 codes, per row
    const int code0 = nc * 64 + tx * 4;
    const float c0 = cnorm[code0 + 0], c1 = cnorm[code0 + 1];
    const float c2 = cnorm[code0 + 2], c3 = cnorm[code0 + 3];
#pragma unroll
    for (int i = 0; i < 4; ++i) {
      const float d0 = c0 - 2.f * acc[i][0];
      const float d1 = c1 - 2.f * acc[i][1];
      const float d2 = c2 - 2.f * acc[i][2];
      const float d3 = c3 - 2.f * acc[i][3];
      float bv = d0; int bi = code0;
      if (d1 < bv) { bv = d1; bi = code0 + 1; }
      if (d2 < bv) { bv = d2; bi = code0 + 2; }
      if (d3 < bv) { bv = d3; bi = code0 + 3; }
      redv[ty * 4 + i][tx] = bv;
      redi[ty * 4 + i][tx] = bi;
    }
    __syncthreads();
    if (tid < 64) {  // merge 16 column-groups, ascending => first-min semantics
      float bv = bestv[tid]; int bi = besti[tid];
#pragma unroll
      for (int t = 0; t < 16; ++t) {
        const float v = redv[tid][t]; const int ix = redi[tid][t];
        if (v < bv || (v == bv && ix < bi)) { bv = v; bi = ix; }
      }
      bestv[tid] = bv; besti[tid] = bi;
    }
    // redv/redi reused only after the __syncthreads at top of next kc loop
  }
  __syncthreads();

  // gather + commit + residual update: thread = dim, loop over 64 tokens
  float csum = 0.f;
  for (int token = 0; token < 64; ++token) {
    const int code = besti[token];
    const float q = cb[(size_t)code * DDIM + tid];
    const size_t gi = (size_t)(m0 + token) * DDIM + tid;
    const float old = r[gi];
    const float diff = q - old;
    csum += diff * diff;
    r[gi] = old - q;
    if (nq == 0)      { qsum[gi] = q;  q1[gi] = q; }
    else if (nq == 1) { qsum[gi] += q; q2[gi] = q; }
    else              { qsum[gi] += q; }
  }
  redc[tid] = csum;
  __syncthreads();
  for (int s = 128; s > 0; s >>= 1) {
    if (tid < s) redc[tid] += redc[tid + s];
    __syncthreads();
  }
  if (tid == 0) atomicAdd(commitAcc, redc[0]);
}

__global__ void zero_one(float* p) { p[0] = 0.f; }

__global__ void finalize_com(const float* __restrict__ a, float* __restrict__ o) {
  // com = mean over NQ of mean over (B,T,D) of diff^2, COMMIT_W = 1
  o[0] = a[0] * (1.0f / (float)((size_t)NQUANT * BT * DDIM));
}

extern "C" void kernel_launch(void* const* d_in, const int* in_sizes, int n_in,
                              void* d_out, int out_size, void* d_ws, size_t ws_size,
                              hipStream_t stream) {
  (void)in_sizes; (void)n_in; (void)out_size; (void)ws_size;
  const float* x     = (const float*)d_in[0];
  const float* W_in  = (const float*)d_in[1];
  const float* b_in  = (const float*)d_in[2];
  const float* W_out = (const float*)d_in[3];
  const float* b_out = (const float*)d_in[4];
  const float* cbs   = (const float*)d_in[5];

  float* out = (float*)d_out;                       // [BT, HIDDEN]
  float* q1  = out + (size_t)BT * HIDDEN;           // [BT, DDIM]
  float* q2  = q1 + (size_t)BT * DDIM;              // [BT, DDIM]
  float* com = q2 + (size_t)BT * DDIM;              // [1]

  float* r         = (float*)d_ws;                  // [BT, DDIM] residual
  float* qsum      = r + (size_t)BT * DDIM;         // [BT, DDIM]
  float* cnorm     = qsum + (size_t)BT * DDIM;      // [NQ*K]
  float* commitAcc = cnorm + NQUANT * KCODE;        // [1]

  cnorm_kernel<<<NQUANT * KCODE, 256, 0, stream>>>(cbs, cnorm);
  gemm_nt<<<dim3(BT / 64, DDIM / 64), 256, 0, stream>>>(x, W_in, b_in, r, DDIM, HIDDEN);
  zero_one<<<1, 1, 0, stream>>>(commitAcc);
  for (int nq = 0; nq < NQUANT; ++nq) {
    rvq_step<<<BT / 64, 256, 0, stream>>>(r, cbs + (size_t)nq * KCODE * DDIM,
                                          cnorm + nq * KCODE, qsum, q1, q2,
                                          commitAcc, nq);
  }
  gemm_nt<<<dim3(BT / 64, HIDDEN / 64), 256, 0, stream>>>(qsum, W_out, b_out, out, HIDDEN, DDIM);
  finalize_com<<<1, 1, 0, stream>>>(commitAcc, com);
}

// Round 2
// 1479.738 us; speedup vs baseline: 2.5542x; 2.5542x over previous
//
#include <hip/hip_runtime.h>

#define BT     32768
#define HIDDEN 512
#define DDIM   256
#define KCODE  1024
#define NQUANT 8

typedef _Float16 f16;
typedef _Float16 f16x4 __attribute__((ext_vector_type(4)));
typedef _Float16 f16x8 __attribute__((ext_vector_type(8)));
typedef float f32x4 __attribute__((ext_vector_type(4)));

#define LO_SCALE 64.0f
#define LO_INV   0.015625f

// ---------------------------------------------------------------------------
// cnorm: ||c||^2 for every code of every quantizer (fp32, from fp32 codebook)
// ---------------------------------------------------------------------------
__global__ __launch_bounds__(256) void cnorm_kernel(const float* __restrict__ cb,
                                                    float* __restrict__ cnorm) {
  __shared__ float red[256];
  const int code = blockIdx.x;
  const float v = cb[(size_t)code * DDIM + threadIdx.x];
  red[threadIdx.x] = v * v;
  __syncthreads();
  for (int s = 128; s > 0; s >>= 1) {
    if (threadIdx.x < s) red[threadIdx.x] += red[threadIdx.x + s];
    __syncthreads();
  }
  if (threadIdx.x == 0) cnorm[code] = red[0];
}

// ---------------------------------------------------------------------------
// codebook -> f16 hi/lo extended form: cbext[code][0..255]=hi, [256..511]=lo*64
// one quantizer per launch. grid 1024 x 256.
// ---------------------------------------------------------------------------
__global__ __launch_bounds__(256) void cbext_conv(const float* __restrict__ cb,
                                                  f16* __restrict__ cbext) {
  const int idx = blockIdx.x * 256 + threadIdx.x;  // 1024*256
  const int c = idx >> 8, d = idx & 255;
  const float v = cb[idx];
  const f16 hi = (f16)v;
  const f16 lo = (f16)((v - (float)hi) * LO_SCALE);
  cbext[(size_t)c * 512 + d] = hi;
  cbext[(size_t)c * 512 + 256 + d] = lo;
}

// ---------------------------------------------------------------------------
// proj_in: h = x @ W_in^T + b_in, stored as hi/lo f16 pairs into rext.
// 64x64 tile fp32 (not the bottleneck this round). K=512, N=256.
// ---------------------------------------------------------------------------
__global__ __launch_bounds__(256) void gemm_projin(const float* __restrict__ A,
                                                   const float* __restrict__ B,
                                                   const float* __restrict__ bias,
                                                   f16* __restrict__ rext) {
  __shared__ float AsT[64][68];
  __shared__ float BsT[64][68];
  const int tid = threadIdx.x;
  const int tx = tid & 15, ty = tid >> 4;
  const int m0 = blockIdx.x * 64, n0 = blockIdx.y * 64;
  float acc[4][4] = {{0.f}};
  for (int kc = 0; kc < HIDDEN; kc += 64) {
    __syncthreads();
#pragma unroll
    for (int v = 0; v < 4; ++v) {
      const int flat = v * 256 + tid;
      const int row = flat >> 4, seg = flat & 15;
      const float4 a4 = *(const float4*)&A[(size_t)(m0 + row) * HIDDEN + kc + seg * 4];
      AsT[seg * 4 + 0][row] = a4.x; AsT[seg * 4 + 1][row] = a4.y;
      AsT[seg * 4 + 2][row] = a4.z; AsT[seg * 4 + 3][row] = a4.w;
      const float4 b4 = *(const float4*)&B[(size_t)(n0 + row) * HIDDEN + kc + seg * 4];
      BsT[seg * 4 + 0][row] = b4.x; BsT[seg * 4 + 1][row] = b4.y;
      BsT[seg * 4 + 2][row] = b4.z; BsT[seg * 4 + 3][row] = b4.w;
    }
    __syncthreads();
#pragma unroll
    for (int k = 0; k < 64; ++k) {
      const float4 a = *(const float4*)&AsT[k][ty * 4];
      const float4 b = *(const float4*)&BsT[k][tx * 4];
      acc[0][0] += a.x * b.x; acc[0][1] += a.x * b.y; acc[0][2] += a.x * b.z; acc[0][3] += a.x * b.w;
      acc[1][0] += a.y * b.x; acc[1][1] += a.y * b.y; acc[1][2] += a.y * b.z; acc[1][3] += a.y * b.w;
      acc[2][0] += a.z * b.x; acc[2][1] += a.z * b.y; acc[2][2] += a.z * b.z; acc[2][3] += a.z * b.w;
      acc[3][0] += a.w * b.x; acc[3][1] += a.w * b.y; acc[3][2] += a.w * b.z; acc[3][3] += a.w * b.w;
    }
  }
  const float4 bb = *(const float4*)&bias[n0 + tx * 4];
#pragma unroll
  for (int i = 0; i < 4; ++i) {
    const float o0 = acc[i][0] + bb.x, o1 = acc[i][1] + bb.y;
    const float o2 = acc[i][2] + bb.z, o3 = acc[i][3] + bb.w;
    f16x4 hv, lv;
    const f16 h0 = (f16)o0; hv[0] = h0; lv[0] = (f16)((o0 - (float)h0) * LO_SCALE);
    const f16 h1 = (f16)o1; hv[1] = h1; lv[1] = (f16)((o1 - (float)h1) * LO_SCALE);
    const f16 h2 = (f16)o2; hv[2] = h2; lv[2] = (f16)((o2 - (float)h2) * LO_SCALE);
    const f16 h3 = (f16)o3; hv[3] = h3; lv[3] = (f16)((o3 - (float)h3) * LO_SCALE);
    const size_t base = (size_t)(m0 + ty * 4 + i) * 512;
    *(f16x4*)&rext[base + n0 + tx * 4] = hv;
    *(f16x4*)&rext[base + 256 + n0 + tx * 4] = lv;
  }
}

// ---------------------------------------------------------------------------
// fp32 NT GEMM for proj_out (unchanged from round 1).
// ---------------------------------------------------------------------------
__global__ __launch_bounds__(256) void gemm_nt(const float* __restrict__ A,
                                               const float* __restrict__ B,
                                               const float* __restrict__ bias,
                                               float* __restrict__ C,
                                               int N, int K) {
  __shared__ float AsT[64][68];
  __shared__ float BsT[64][68];
  const int tid = threadIdx.x;
  const int tx = tid & 15, ty = tid >> 4;
  const int m0 = blockIdx.x * 64, n0 = blockIdx.y * 64;
  float acc[4][4] = {{0.f}};
  for (int kc = 0; kc < K; kc += 64) {
    __syncthreads();
#pragma unroll
    for (int v = 0; v < 4; ++v) {
      const int flat = v * 256 + tid;
      const int row = flat >> 4, seg = flat & 15;
      const float4 a4 = *(const float4*)&A[(size_t)(m0 + row) * K + kc + seg * 4];
      AsT[seg * 4 + 0][row] = a4.x; AsT[seg * 4 + 1][row] = a4.y;
      AsT[seg * 4 + 2][row] = a4.z; AsT[seg * 4 + 3][row] = a4.w;
      const float4 b4 = *(const float4*)&B[(size_t)(n0 + row) * K + kc + seg * 4];
      BsT[seg * 4 + 0][row] = b4.x; BsT[seg * 4 + 1][row] = b4.y;
      BsT[seg * 4 + 2][row] = b4.z; BsT[seg * 4 + 3][row] = b4.w;
    }
    __syncthreads();
#pragma unroll
    for (int k = 0; k < 64; ++k) {
      const float4 a = *(const float4*)&AsT[k][ty * 4];
      const float4 b = *(const float4*)&BsT[k][tx * 4];
      acc[0][0] += a.x * b.x; acc[0][1] += a.x * b.y; acc[0][2] += a.x * b.z; acc[0][3] += a.x * b.w;
      acc[1][0] += a.y * b.x; acc[1][1] += a.y * b.y; acc[1][2] += a.y * b.z; acc[1][3] += a.y * b.w;
      acc[2][0] += a.z * b.x; acc[2][1] += a.z * b.y; acc[2][2] += a.z * b.z; acc[2][3] += a.z * b.w;
      acc[3][0] += a.w * b.x; acc[3][1] += a.w * b.y; acc[3][2] += a.w * b.z; acc[3][3] += a.w * b.w;
    }
  }
  const float4 bb = *(const float4*)&bias[n0 + tx * 4];
#pragma unroll
  for (int i = 0; i < 4; ++i) {
    float4 o;
    o.x = acc[i][0] + bb.x; o.y = acc[i][1] + bb.y;
    o.z = acc[i][2] + bb.z; o.w = acc[i][3] + bb.w;
    *(float4*)&C[(size_t)(m0 + ty * 4 + i) * N + n0 + tx * 4] = o;
  }
}

// ---------------------------------------------------------------------------
// RVQ step, MFMA version.
// Block = 64 tokens, 4 waves (2x2), wave tile 32 tokens x 64 codes.
// Codes processed in 8 chunks of 128. K-GEMM is K=768 f16:
//   t 0-3 : hi_r * hi_c            -> acc
//   t 4-7 : hi_r * (lo_c*64)       -> acc2
//   t 8-11: (lo_r*64) * hi_c       -> acc2
// dot = acc + acc2/64.  d' = cnorm - 2*dot (|r|^2 dropped, argmin-safe).
// LDS XOR-swizzle (slot ^= row&7) applied on BOTH the pre-swizzled
// global_load_lds source and the ds_read side (rule 21).
// ---------------------------------------------------------------------------
__device__ __forceinline__ void stage_step(int s, int buf, int m0,
                                           const f16* __restrict__ rext,
                                           const f16* __restrict__ cbext,
                                           f16* At, f16* Bt, int tid) {
  const int w = tid >> 6, l = tid & 63;
  const int chunk = s / 12, t = s % 12;
  const int k0 = t * 64;
  const int kA0 = (t < 4) ? k0 : k0 - 256;   // hi, hi, lo
  const int kB0 = (t < 8) ? k0 : k0 - 512;   // hi, lo, hi
  const int lrow = l >> 3;                   // 0..7 within 8-row issue
  const int logslot = (l & 7) ^ (lrow & 7);  // inverse-swizzled source slot
#pragma unroll
  for (int i = 0; i < 2; ++i) {              // A: 8 issues of 1KB, 2 per wave
    const int q = w * 2 + i;
    const int row = q * 8 + lrow;
    const f16* src = rext + (size_t)(m0 + row) * 512 + kA0 + logslot * 8;
    __builtin_amdgcn_global_load_lds(
        (const __attribute__((address_space(1))) void*)src,
        (__attribute__((address_space(3))) void*)(At + buf * (64 * 64) + q * 512),
        16, 0, 0);
  }
#pragma unroll
  for (int i = 0; i < 4; ++i) {              // B: 16 issues, 4 per wave
    const int q = w * 4 + i;
    const int row = q * 8 + lrow;
    const f16* src = cbext + (size_t)(chunk * 128 + row) * 512 + kB0 + logslot * 8;
    __builtin_amdgcn_global_load_lds(
        (const __attribute__((address_space(1))) void*)src,
        (__attribute__((address_space(3))) void*)(Bt + buf * (128 * 64) + q * 512),
        16, 0, 0);
  }
}

__global__ __launch_bounds__(256) void rvq_step_mfma(
    f16* __restrict__ rext, const f16* __restrict__ cbext,
    const float* __restrict__ cbf32, const float* __restrict__ cnormq,
    float* __restrict__ qsum, float* __restrict__ q1, float* __restrict__ q2,
    float* __restrict__ commitAcc, int nq) {
  __shared__ __align__(16) f16 At[2 * 64 * 64];    // 16 KB
  __shared__ __align__(16) f16 Bt[2 * 128 * 64];   // 32 KB
  __shared__ float mv[2][64];
  __shared__ int   mi[2][64];
  __shared__ float bv[64];
  __shared__ int   bidx[64];
  __shared__ float redc[256];
  const int tid = threadIdx.x;
  const int w = tid >> 6, l = tid & 63;
  const int wr = w >> 1, wc = w & 1;
  const int lj = l & 15, li = l >> 4;
  const int m0 = blockIdx.x * 64;

  if (tid < 64) { bv[tid] = 3.0e38f; bidx[tid] = 0; }
  stage_step(0, 0, m0, rext, cbext, At, Bt, tid);
  asm volatile("s_waitcnt vmcnt(0)" ::: "memory");
  __syncthreads();

  for (int chunk = 0; chunk < 8; ++chunk) {
    f32x4 acc[2][4], acc2[2][4];
#pragma unroll
    for (int m = 0; m < 2; ++m)
#pragma unroll
      for (int n = 0; n < 4; ++n) { acc[m][n] = (f32x4){0.f, 0.f, 0.f, 0.f}; acc2[m][n] = (f32x4){0.f, 0.f, 0.f, 0.f}; }

    for (int t = 0; t < 12; ++t) {
      const int s = chunk * 12 + t;
      const int buf = s & 1;
      if (s + 1 < 96) stage_step(s + 1, buf ^ 1, m0, rext, cbext, At, Bt, tid);
      const f16* Ab = At + buf * (64 * 64);
      const f16* Bb = Bt + buf * (128 * 64);
      f16x8 af[2][2], bf[4][2];
#pragma unroll
      for (int m = 0; m < 2; ++m)
#pragma unroll
        for (int kk = 0; kk < 2; ++kk) {
          const int row = wr * 32 + m * 16 + lj;
          const int slot = ((kk << 2) | li) ^ (row & 7);
          af[m][kk] = *(const f16x8*)((const char*)Ab + row * 128 + slot * 16);
        }
#pragma unroll
      for (int n = 0; n < 4; ++n)
#pragma unroll
        for (int kk = 0; kk < 2; ++kk) {
          const int row = wc * 64 + n * 16 + lj;
          const int slot = ((kk << 2) | li) ^ (row & 7);
          bf[n][kk] = *(const f16x8*)((const char*)Bb + row * 128 + slot * 16);
        }
      if (t < 4) {
#pragma unroll
        for (int m = 0; m < 2; ++m)
#pragma unroll
          for (int n = 0; n < 4; ++n) {
            acc[m][n] = __builtin_amdgcn_mfma_f32_16x16x32_f16(af[m][0], bf[n][0], acc[m][n], 0, 0, 0);
            acc[m][n] = __builtin_amdgcn_mfma_f32_16x16x32_f16(af[m][1], bf[n][1], acc[m][n], 0, 0, 0);
          }
      } else {
#pragma unroll
        for (int m = 0; m < 2; ++m)
#pragma unroll
          for (int n = 0; n < 4; ++n) {
            acc2[m][n] = __builtin_amdgcn_mfma_f32_16x16x32_f16(af[m][0], bf[n][0], acc2[m][n], 0, 0, 0);
            acc2[m][n] = __builtin_amdgcn_mfma_f32_16x16x32_f16(af[m][1], bf[n][1], acc2[m][n], 0, 0, 0);
          }
      }
      asm volatile("s_waitcnt vmcnt(0)" ::: "memory");
      __syncthreads();
    }

    // distances + per-lane argmin (first-occurrence: n ascending, strict <)
    float bvv[2][4]; int bii[2][4];
#pragma unroll
    for (int m = 0; m < 2; ++m)
#pragma unroll
      for (int j = 0; j < 4; ++j) { bvv[m][j] = 3.0e38f; bii[m][j] = 0; }
#pragma unroll
    for (int n = 0; n < 4; ++n) {
      const int cl = wc * 64 + n * 16 + lj;
      const float cn = cnormq[chunk * 128 + cl];
#pragma unroll
      for (int m = 0; m < 2; ++m)
#pragma unroll
        for (int j = 0; j < 4; ++j) {
          const float d = cn - 2.0f * (acc[m][n][j] + acc2[m][n][j] * LO_INV);
          if (d < bvv[m][j]) { bvv[m][j] = d; bii[m][j] = cl; }
        }
    }
    // cross-lane (code axis = lj) reduce, tie -> lower index
#pragma unroll
    for (int off = 1; off < 16; off <<= 1) {
#pragma unroll
      for (int m = 0; m < 2; ++m)
#pragma unroll
        for (int j = 0; j < 4; ++j) {
          const float ov = __shfl_xor(bvv[m][j], off);
          const int oi = __shfl_xor(bii[m][j], off);
          if (ov < bvv[m][j] || (ov == bvv[m][j] && oi < bii[m][j])) { bvv[m][j] = ov; bii[m][j] = oi; }
        }
    }
    if (lj == 0) {
#pragma unroll
      for (int m = 0; m < 2; ++m)
#pragma unroll
        for (int j = 0; j < 4; ++j) {
          const int tl = wr * 32 + m * 16 + li * 4 + j;
          mv[wc][tl] = bvv[m][j]; mi[wc][tl] = chunk * 128 + bii[m][j];
        }
    }
    __syncthreads();
    if (tid < 64) {  // wc=0 codes < wc=1 codes; earlier chunk = lower idx
      float v0 = mv[0][tid]; int i0 = mi[0][tid];
      const float v1 = mv[1][tid]; const int i1 = mi[1][tid];
      if (v1 < v0) { v0 = v1; i0 = i1; }
      if (v0 < bv[tid]) { bv[tid] = v0; bidx[tid] = i0; }
    }
    // next mv write only after 12 barriers of next chunk's K-loop
  }
  __syncthreads();

  // gather + commit + residual update. thread = dim, loop over 64 tokens.
  float csum = 0.f;
  for (int tok = 0; tok < 64; ++tok) {
    const int code = bidx[tok];
    const float qv = cbf32[(size_t)code * DDIM + tid];
    const size_t rbase = (size_t)(m0 + tok) * 512;
    const float rh = (float)rext[rbase + tid];
    const float rl = (float)rext[rbase + 256 + tid] * LO_INV;
    const float rold = rh + rl;
    const float diff = qv - rold;
    csum += diff * diff;
    const float rnew = rold - qv;
    const f16 nh = (f16)rnew;
    const f16 nl = (f16)((rnew - (float)nh) * LO_SCALE);
    rext[rbase + tid] = nh;
    rext[rbase + 256 + tid] = nl;
    const size_t gi = (size_t)(m0 + tok) * DDIM + tid;
    if (nq == 0)      { qsum[gi] = qv;  q1[gi] = qv; }
    else if (nq == 1) { qsum[gi] += qv; q2[gi] = qv; }
    else              { qsum[gi] += qv; }
  }
  redc[tid] = csum;
  __syncthreads();
  for (int s2 = 128; s2 > 0; s2 >>= 1) {
    if (tid < s2) redc[tid] += redc[tid + s2];
    __syncthreads();
  }
  if (tid == 0) atomicAdd(commitAcc, redc[0]);
}

__global__ void zero_one(float* p) { p[0] = 0.f; }

__global__ void finalize_com(const float* __restrict__ a, float* __restrict__ o) {
  o[0] = a[0] * (1.0f / (float)((size_t)NQUANT * BT * DDIM));
}

extern "C" void kernel_launch(void* const* d_in, const int* in_sizes, int n_in,
                              void* d_out, int out_size, void* d_ws, size_t ws_size,
                              hipStream_t stream) {
  (void)in_sizes; (void)n_in; (void)out_size; (void)ws_size;
  const float* x     = (const float*)d_in[0];
  const float* W_in  = (const float*)d_in[1];
  const float* b_in  = (const float*)d_in[2];
  const float* W_out = (const float*)d_in[3];
  const float* b_out = (const float*)d_in[4];
  const float* cbs   = (const float*)d_in[5];

  float* out = (float*)d_out;                        // [BT, HIDDEN]
  float* q1  = out + (size_t)BT * HIDDEN;            // [BT, DDIM]
  float* q2  = q1 + (size_t)BT * DDIM;               // [BT, DDIM]
  float* com = q2 + (size_t)BT * DDIM;               // [1]

  f16*   rext      = (f16*)d_ws;                     // [BT][512] hi|lo  (32 MB)
  float* qsum      = (float*)(rext + (size_t)BT * 512);  // [BT][256]    (32 MB)
  f16*   cbext     = (f16*)(qsum + (size_t)BT * DDIM);   // [1024][512]  (1 MB, per-step reuse)
  float* cnorm     = (float*)(cbext + (size_t)KCODE * 512);  // [NQ*K]
  float* commitAcc = cnorm + NQUANT * KCODE;

  cnorm_kernel<<<NQUANT * KCODE, 256, 0, stream>>>(cbs, cnorm);
  gemm_projin<<<dim3(BT / 64, DDIM / 64), 256, 0, stream>>>(x, W_in, b_in, rext);
  zero_one<<<1, 1, 0, stream>>>(commitAcc);
  for (int nq = 0; nq < NQUANT; ++nq) {
    const float* cbq = cbs + (size_t)nq * KCODE * DDIM;
    cbext_conv<<<KCODE, 256, 0, stream>>>(cbq, cbext);
    rvq_step_mfma<<<BT / 64, 256, 0, stream>>>(rext, cbext, cbq,
                                               cnorm + nq * KCODE, qsum, q1, q2,
                                               commitAcc, nq);
  }
  gemm_nt<<<dim3(BT / 64, HIDDEN / 64), 256, 0, stream>>>(qsum, W_out, b_out, out, HIDDEN, DDIM);
  finalize_com<<<1, 1, 0, stream>>>(commitAcc, com);
}